// Round 1
// baseline (2364.125 us; speedup 1.0000x reference)
//
#include <hip/hip_runtime.h>

typedef __attribute__((ext_vector_type(8))) short short8;
typedef __attribute__((ext_vector_type(8))) unsigned short ushort8;
typedef __attribute__((ext_vector_type(4))) float floatx4;

#define NUM_AUTHORS 200000
#define HID 128
#define LDK 136  // LDS row stride in bf16 elems (128 + 8 pad, keeps 16B alignment)

__device__ __forceinline__ unsigned short f32_to_bf16(float f) {
  union { float f; unsigned int u; } v; v.f = f;
  unsigned int u = v.u;
  u += 0x7FFF + ((u >> 16) & 1);   // round-to-nearest-even
  return (unsigned short)(u >> 16);
}

// Transpose + convert W[128][128] fp32 -> Wt[n][k] bf16. blockIdx.x selects matrix.
__global__ __launch_bounds__(256) void prep_w(
    const float* __restrict__ Wp, const float* __restrict__ Wa,
    unsigned short* __restrict__ WtP, unsigned short* __restrict__ WtA)
{
  const float* W = blockIdx.x ? Wa : Wp;
  unsigned short* Wt = blockIdx.x ? WtA : WtP;
  int t = threadIdx.x;
#pragma unroll
  for (int i = 0; i < 64; ++i) {
    int g = i * 256 + t;
    int k = g >> 7, n = g & 127;
    Wt[n * HID + k] = f32_to_bf16(W[k * HID + n]);
  }
}

// Y[M,128] = rowscale(X[M,128]) @ W[128,128] + bias
// rowscale = 1/max(counts[row],1) if counts != nullptr (applied post-GEMM; commutes)
// 256 threads = 4 waves; block tile 64 rows x 128 cols; K=128 fully in LDS.
__global__ __launch_bounds__(256) void gemm_mfma(
    const float* __restrict__ X, const unsigned short* __restrict__ Wt,
    const float* __restrict__ bias, const float* __restrict__ counts,
    float* __restrict__ Y, int M)
{
  __shared__ unsigned short As[64 * LDK];    // X tile, bf16 [row][k]
  __shared__ unsigned short Bs[128 * LDK];   // Wt,     bf16 [col][k]
  const int t = threadIdx.x;
  const int row0 = blockIdx.x * 64;

  // stage Wt -> Bs (16B chunks, already bf16)
#pragma unroll
  for (int i = 0; i < 8; ++i) {
    int g = i * 256 + t;           // 2048 groups of 8 elems
    int n = g >> 4;
    int k8 = (g & 15) * 8;
    *(ushort8*)&Bs[n * LDK + k8] = *(const ushort8*)&Wt[n * HID + k8];
  }
  // stage X -> As (fp32 -> bf16)
#pragma unroll
  for (int i = 0; i < 4; ++i) {
    int g = i * 256 + t;           // 1024 groups of 8 elems
    int r = g >> 4;
    int k8 = (g & 15) * 8;
    int row = row0 + r;
    float xv[8];
    if (row < M) {
      const float4* src = (const float4*)(X + (size_t)row * HID + k8);
      float4 x0 = src[0], x1 = src[1];
      xv[0]=x0.x; xv[1]=x0.y; xv[2]=x0.z; xv[3]=x0.w;
      xv[4]=x1.x; xv[5]=x1.y; xv[6]=x1.z; xv[7]=x1.w;
    } else {
#pragma unroll
      for (int j = 0; j < 8; ++j) xv[j] = 0.f;
    }
    ushort8 h;
#pragma unroll
    for (int j = 0; j < 8; ++j) h[j] = f32_to_bf16(xv[j]);
    *(ushort8*)&As[r * LDK + k8] = h;
  }
  __syncthreads();

  const int w = t >> 6;        // wave id: rows w*16..w*16+15
  const int lane = t & 63;
  const int m = lane & 15;     // A row / B col / D col
  const int q = lane >> 4;     // quad: k-group for A/B, row-group for D

  floatx4 acc[8];
#pragma unroll
  for (int c = 0; c < 8; ++c) acc[c] = (floatx4)(0.f);

#pragma unroll
  for (int ks = 0; ks < 4; ++ks) {
    const int koff = ks * 32 + q * 8;
    short8 a = *(const short8*)&As[(w * 16 + m) * LDK + koff];
#pragma unroll
    for (int c = 0; c < 8; ++c) {
      short8 b = *(const short8*)&Bs[(c * 16 + m) * LDK + koff];
      acc[c] = __builtin_amdgcn_mfma_f32_16x16x32_bf16(a, b, acc[c], 0, 0, 0);
    }
  }

  // epilogue: D lane(m,q) reg j -> row q*4+j (within wave tile), col m (within col tile)
  const int rbase = row0 + w * 16 + q * 4;
  float inv[4];
#pragma unroll
  for (int j = 0; j < 4; ++j) {
    if (counts) {
      int row = rbase + j;
      float c = (row < M) ? counts[row] : 1.0f;
      inv[j] = 1.0f / fmaxf(c, 1.0f);
    } else {
      inv[j] = 1.0f;
    }
  }
#pragma unroll
  for (int c = 0; c < 8; ++c) {
    const int col = c * 16 + m;
    const float bv = bias[col];
#pragma unroll
    for (int j = 0; j < 4; ++j) {
      int row = rbase + j;
      if (row < M) Y[(size_t)row * HID + col] = acc[c][j] * inv[j] + bv;
    }
  }
}

// One wave per edge: sums[a] += paper_h[p], counts[a] += 1
__global__ __launch_bounds__(256) void scatter_kernel(
    const float* __restrict__ paper_h, const int* __restrict__ author_ids,
    const int* __restrict__ paper_ids, float* __restrict__ sums,
    float* __restrict__ counts, int nedges)
{
  int wid = blockIdx.x * 4 + (threadIdx.x >> 6);
  if (wid >= nedges) return;
  int lane = threadIdx.x & 63;
  int a = author_ids[wid];
  int p = paper_ids[wid];
  float2 v = ((const float2*)(paper_h + (size_t)p * HID))[lane];
  float* dst = sums + (size_t)a * HID + lane * 2;
  unsafeAtomicAdd(dst, v.x);
  unsafeAtomicAdd(dst + 1, v.y);
  if (lane == 0) unsafeAtomicAdd(counts + a, 1.0f);
}

// One wave per label edge: out[e] = dot(author_h[la[e]], paper_h[lp[e]])
__global__ __launch_bounds__(256) void dot_kernel(
    const float* __restrict__ author_h, const float* __restrict__ paper_h,
    const int* __restrict__ la, const int* __restrict__ lp,
    float* __restrict__ out, int n)
{
  int wid = blockIdx.x * 4 + (threadIdx.x >> 6);
  if (wid >= n) return;
  int lane = threadIdx.x & 63;
  int a = la[wid], p = lp[wid];
  float2 av = ((const float2*)(author_h + (size_t)a * HID))[lane];
  float2 pv = ((const float2*)(paper_h + (size_t)p * HID))[lane];
  float s = av.x * pv.x + av.y * pv.y;
#pragma unroll
  for (int off = 32; off > 0; off >>= 1) s += __shfl_xor(s, off, 64);
  if (lane == 0) out[wid] = s;
}

extern "C" void kernel_launch(void* const* d_in, const int* in_sizes, int n_in,
                              void* d_out, int out_size, void* d_ws, size_t ws_size,
                              hipStream_t stream)
{
  const float* paper_x         = (const float*)d_in[0];
  const int*   author_ids      = (const int*)d_in[1];
  const int*   paper_ids       = (const int*)d_in[2];
  const int*   label_author_ids= (const int*)d_in[3];
  const int*   label_paper_ids = (const int*)d_in[4];
  const float* W_paper         = (const float*)d_in[5];
  const float* b_paper         = (const float*)d_in[6];
  const float* W_author        = (const float*)d_in[7];
  const float* b_author        = (const float*)d_in[8];
  float* out = (float*)d_out;

  const int num_papers = in_sizes[0] / HID;
  const int num_edges  = in_sizes[1];
  const int num_label  = in_sizes[3];

  char* ws = (char*)d_ws;
  size_t off = 0;
  float* paper_h = (float*)(ws + off); off += (size_t)num_papers * HID * 4;
  float* sums    = (float*)(ws + off); off += (size_t)NUM_AUTHORS * HID * 4;
  float* counts  = (float*)(ws + off); off += (size_t)NUM_AUTHORS * 4;       // contiguous after sums
  float* author_h= (float*)(ws + off); off += (size_t)NUM_AUTHORS * HID * 4;
  unsigned short* WtP = (unsigned short*)(ws + off); off += HID * HID * 2;
  unsigned short* WtA = (unsigned short*)(ws + off); off += HID * HID * 2;

  // zero sums + counts (one contiguous region)
  hipMemsetAsync(sums, 0, (size_t)NUM_AUTHORS * HID * 4 + (size_t)NUM_AUTHORS * 4, stream);

  prep_w<<<2, 256, 0, stream>>>(W_paper, W_author, WtP, WtA);

  gemm_mfma<<<(num_papers + 63) / 64, 256, 0, stream>>>(
      paper_x, WtP, b_paper, nullptr, paper_h, num_papers);

  scatter_kernel<<<(num_edges + 3) / 4, 256, 0, stream>>>(
      paper_h, author_ids, paper_ids, sums, counts, num_edges);

  gemm_mfma<<<(NUM_AUTHORS + 63) / 64, 256, 0, stream>>>(
      sums, WtA, b_author, counts, author_h, NUM_AUTHORS);

  dot_kernel<<<(num_label + 3) / 4, 256, 0, stream>>>(
      author_h, paper_h, label_author_ids, label_paper_ids, out, num_label);
}

// Round 2
// 1041.560 us; speedup vs baseline: 2.2698x; 2.2698x over previous
//
#include <hip/hip_runtime.h>

typedef __attribute__((ext_vector_type(8))) short short8;
typedef __attribute__((ext_vector_type(8))) unsigned short ushort8;
typedef __attribute__((ext_vector_type(4))) float floatx4;

#define NUM_AUTHORS 200000
#define HID 128
#define LDK 136  // LDS row stride in bf16 elems (128 + 8 pad, 16B-aligned)

__device__ __forceinline__ unsigned short f32_to_bf16(float f) {
  union { float f; unsigned int u; } v; v.f = f;
  unsigned int u = v.u;
  u += 0x7FFF + ((u >> 16) & 1);   // round-to-nearest-even
  return (unsigned short)(u >> 16);
}
__device__ __forceinline__ float bf16lo_to_f32(unsigned int packed) {
  union { unsigned int u; float f; } v; v.u = packed << 16; return v.f;
}
__device__ __forceinline__ float bf16hi_to_f32(unsigned int packed) {
  union { unsigned int u; float f; } v; v.u = packed & 0xFFFF0000u; return v.f;
}

// Transpose + convert W[128][128] fp32 -> Wt[n][k] bf16. blockIdx.x selects matrix.
__global__ __launch_bounds__(256) void prep_w(
    const float* __restrict__ Wp, const float* __restrict__ Wa,
    unsigned short* __restrict__ WtP, unsigned short* __restrict__ WtA)
{
  const float* W = blockIdx.x ? Wa : Wp;
  unsigned short* Wt = blockIdx.x ? WtA : WtP;
  int t = threadIdx.x;
#pragma unroll
  for (int i = 0; i < 64; ++i) {
    int g = i * 256 + t;
    int k = g >> 7, n = g & 127;
    Wt[n * HID + k] = f32_to_bf16(W[k * HID + n]);
  }
}

// Y[M,128](bf16) = rowscale(X[M,128]) @ W[128,128] + bias
// rowscale = 1/max(counts[row],1) if counts != nullptr
// X is fp32 (X_IS_BF16=false) or bf16 (true). 4 waves; 64-row x 128-col tile.
template<bool X_IS_BF16>
__global__ __launch_bounds__(256) void gemm_mfma(
    const void* __restrict__ Xv, const unsigned short* __restrict__ Wt,
    const float* __restrict__ bias, const int* __restrict__ counts,
    unsigned short* __restrict__ Y, int M)
{
  __shared__ unsigned short As[64 * LDK];    // X tile, bf16 [row][k]
  __shared__ unsigned short Bs[128 * LDK];   // Wt,     bf16 [col][k]
  const int t = threadIdx.x;
  const int row0 = blockIdx.x * 64;

  // stage Wt -> Bs (16B chunks)
#pragma unroll
  for (int i = 0; i < 8; ++i) {
    int g = i * 256 + t;           // 2048 groups of 8 elems
    int n = g >> 4;
    int k8 = (g & 15) * 8;
    *(ushort8*)&Bs[n * LDK + k8] = *(const ushort8*)&Wt[n * HID + k8];
  }
  // stage X -> As
#pragma unroll
  for (int i = 0; i < 4; ++i) {
    int g = i * 256 + t;           // 1024 groups of 8 elems
    int r = g >> 4;
    int k8 = (g & 15) * 8;
    int row = row0 + r;
    ushort8 h;
    if (X_IS_BF16) {
      const unsigned short* X = (const unsigned short*)Xv;
      if (row < M) h = *(const ushort8*)(X + (size_t)row * HID + k8);
      else { ushort8 z = (ushort8)0; h = z; }
    } else {
      const float* X = (const float*)Xv;
      float xv[8];
      if (row < M) {
        const float4* src = (const float4*)(X + (size_t)row * HID + k8);
        float4 x0 = src[0], x1 = src[1];
        xv[0]=x0.x; xv[1]=x0.y; xv[2]=x0.z; xv[3]=x0.w;
        xv[4]=x1.x; xv[5]=x1.y; xv[6]=x1.z; xv[7]=x1.w;
      } else {
#pragma unroll
        for (int j = 0; j < 8; ++j) xv[j] = 0.f;
      }
#pragma unroll
      for (int j = 0; j < 8; ++j) h[j] = f32_to_bf16(xv[j]);
    }
    *(ushort8*)&As[r * LDK + k8] = h;
  }
  __syncthreads();

  const int w = t >> 6;        // wave id: rows w*16..w*16+15
  const int lane = t & 63;
  const int m = lane & 15;     // A row / B col / D col
  const int q = lane >> 4;     // quad

  floatx4 acc[8];
#pragma unroll
  for (int c = 0; c < 8; ++c) acc[c] = (floatx4)(0.f);

#pragma unroll
  for (int ks = 0; ks < 4; ++ks) {
    const int koff = ks * 32 + q * 8;
    short8 a = *(const short8*)&As[(w * 16 + m) * LDK + koff];
#pragma unroll
    for (int c = 0; c < 8; ++c) {
      short8 b = *(const short8*)&Bs[(c * 16 + m) * LDK + koff];
      acc[c] = __builtin_amdgcn_mfma_f32_16x16x32_bf16(a, b, acc[c], 0, 0, 0);
    }
  }

  // epilogue: D lane(m,q) reg j -> row q*4+j, col m (within tiles)
  const int rbase = row0 + w * 16 + q * 4;
  float inv[4];
#pragma unroll
  for (int j = 0; j < 4; ++j) {
    if (counts) {
      int row = rbase + j;
      float c = (row < M) ? (float)counts[row] : 1.0f;
      inv[j] = 1.0f / fmaxf(c, 1.0f);
    } else {
      inv[j] = 1.0f;
    }
  }
#pragma unroll
  for (int c = 0; c < 8; ++c) {
    const int col = c * 16 + m;
    const float bv = bias[col];
#pragma unroll
    for (int j = 0; j < 4; ++j) {
      int row = rbase + j;
      if (row < M) Y[(size_t)row * HID + col] = f32_to_bf16(acc[c][j] * inv[j] + bv);
    }
  }
}

// ---- CSR build ----
__global__ __launch_bounds__(256) void hist_kernel(
    const int* __restrict__ aid, int* __restrict__ cnt, int n)
{
  int i = blockIdx.x * 256 + threadIdx.x;
  if (i < n) atomicAdd(&cnt[aid[i]], 1);
}

// per-block exclusive scan (256 elems/block); partial -> offsets, block total -> blockSums
__global__ __launch_bounds__(256) void scan1(
    const int* __restrict__ cnt, int* __restrict__ offsets,
    int* __restrict__ blockSums, int n)
{
  __shared__ int s[256];
  int t = threadIdx.x;
  int i = blockIdx.x * 256 + t;
  int v = (i < n) ? cnt[i] : 0;
  s[t] = v; __syncthreads();
#pragma unroll
  for (int off = 1; off < 256; off <<= 1) {
    int tv = 0;
    if (t >= off) tv = s[t - off];
    __syncthreads();
    if (t >= off) s[t] += tv;
    __syncthreads();
  }
  if (i < n) offsets[i] = s[t] - v;       // exclusive within block
  if (t == 255) blockSums[blockIdx.x] = s[255];
}

// single-block exclusive scan of blockSums (nb <= 1024)
__global__ __launch_bounds__(1024) void scan2(int* __restrict__ blockSums, int nb)
{
  __shared__ int s[1024];
  int t = threadIdx.x;
  int v = (t < nb) ? blockSums[t] : 0;
  s[t] = v; __syncthreads();
#pragma unroll
  for (int off = 1; off < 1024; off <<= 1) {
    int tv = 0;
    if (t >= off) tv = s[t - off];
    __syncthreads();
    if (t >= off) s[t] += tv;
    __syncthreads();
  }
  if (t < nb) blockSums[t] = s[t] - v;    // exclusive
}

__global__ __launch_bounds__(256) void scan3(
    int* __restrict__ offsets, const int* __restrict__ blockSums,
    int* __restrict__ cursor, int n)
{
  int i = blockIdx.x * 256 + threadIdx.x;
  if (i < n) {
    int o = offsets[i] + blockSums[blockIdx.x];
    offsets[i] = o;
    cursor[i]  = o;
  }
}

__global__ __launch_bounds__(256) void reorder_kernel(
    const int* __restrict__ aid, const int* __restrict__ pid,
    int* __restrict__ cursor, int* __restrict__ csr, int n)
{
  int e = blockIdx.x * 256 + threadIdx.x;
  if (e < n) {
    int a = aid[e];
    int pos = atomicAdd(&cursor[a], 1);
    csr[pos] = pid[e];
  }
}

// One wave per author: author_in[a] = sum over its papers of paper_hb rows (bf16 in, fp32 acc, bf16 out)
__global__ __launch_bounds__(256) void accumulate_kernel(
    const unsigned short* __restrict__ paper_hb, const int* __restrict__ csr,
    const int* __restrict__ offsets, const int* __restrict__ cnt,
    unsigned short* __restrict__ author_in)
{
  int a = blockIdx.x * 4 + (threadIdx.x >> 6);
  if (a >= NUM_AUTHORS) return;
  int lane = threadIdx.x & 63;
  int start = offsets[a];
  int n = cnt[a];
  float ax = 0.f, ay = 0.f;
  for (int i = 0; i < n; ++i) {
    int p = csr[start + i];
    unsigned int h = *(const unsigned int*)(paper_hb + (size_t)p * HID + lane * 2);
    ax += bf16lo_to_f32(h);
    ay += bf16hi_to_f32(h);
  }
  unsigned int outw = ((unsigned int)f32_to_bf16(ay) << 16) | (unsigned int)f32_to_bf16(ax);
  *(unsigned int*)(author_in + (size_t)a * HID + lane * 2) = outw;
}

// One wave per label edge: out[e] = dot(author_hb[la[e]], paper_hb[lp[e]])
__global__ __launch_bounds__(256) void dot_kernel(
    const unsigned short* __restrict__ author_hb, const unsigned short* __restrict__ paper_hb,
    const int* __restrict__ la, const int* __restrict__ lp,
    float* __restrict__ out, int n)
{
  int wid = blockIdx.x * 4 + (threadIdx.x >> 6);
  if (wid >= n) return;
  int lane = threadIdx.x & 63;
  int a = la[wid], p = lp[wid];
  unsigned int ah = *(const unsigned int*)(author_hb + (size_t)a * HID + lane * 2);
  unsigned int ph = *(const unsigned int*)(paper_hb + (size_t)p * HID + lane * 2);
  float s = bf16lo_to_f32(ah) * bf16lo_to_f32(ph) + bf16hi_to_f32(ah) * bf16hi_to_f32(ph);
#pragma unroll
  for (int off = 32; off > 0; off >>= 1) s += __shfl_xor(s, off, 64);
  if (lane == 0) out[wid] = s;
}

extern "C" void kernel_launch(void* const* d_in, const int* in_sizes, int n_in,
                              void* d_out, int out_size, void* d_ws, size_t ws_size,
                              hipStream_t stream)
{
  const float* paper_x          = (const float*)d_in[0];
  const int*   author_ids       = (const int*)d_in[1];
  const int*   paper_ids        = (const int*)d_in[2];
  const int*   label_author_ids = (const int*)d_in[3];
  const int*   label_paper_ids  = (const int*)d_in[4];
  const float* W_paper          = (const float*)d_in[5];
  const float* b_paper          = (const float*)d_in[6];
  const float* W_author         = (const float*)d_in[7];
  const float* b_author         = (const float*)d_in[8];
  float* out = (float*)d_out;

  const int num_papers = in_sizes[0] / HID;
  const int num_edges  = in_sizes[1];
  const int num_label  = in_sizes[3];
  const int NA = NUM_AUTHORS;

  char* ws = (char*)d_ws;
  size_t off = 0;
  auto alloc = [&](size_t bytes) { void* p = ws + off; off = (off + bytes + 255) & ~(size_t)255; return p; };
  unsigned short* paper_hb  = (unsigned short*)alloc((size_t)num_papers * HID * 2);
  unsigned short* author_in = (unsigned short*)alloc((size_t)NA * HID * 2);
  unsigned short* author_hb = (unsigned short*)alloc((size_t)NA * HID * 2);
  int* counts_int = (int*)alloc((size_t)NA * 4);
  int* offsets    = (int*)alloc((size_t)NA * 4);
  int* cursor     = (int*)alloc((size_t)NA * 4);
  int* blockSums  = (int*)alloc(1024 * 4);
  int* csr        = (int*)alloc((size_t)num_edges * 4);
  unsigned short* WtP = (unsigned short*)alloc(HID * HID * 2);
  unsigned short* WtA = (unsigned short*)alloc(HID * HID * 2);

  hipMemsetAsync(counts_int, 0, (size_t)NA * 4, stream);

  prep_w<<<2, 256, 0, stream>>>(W_paper, W_author, WtP, WtA);

  gemm_mfma<false><<<(num_papers + 63) / 64, 256, 0, stream>>>(
      paper_x, WtP, b_paper, nullptr, paper_hb, num_papers);

  hist_kernel<<<(num_edges + 255) / 256, 256, 0, stream>>>(author_ids, counts_int, num_edges);

  const int nb = (NA + 255) / 256;   // 782 <= 1024
  scan1<<<nb, 256, 0, stream>>>(counts_int, offsets, blockSums, NA);
  scan2<<<1, 1024, 0, stream>>>(blockSums, nb);
  scan3<<<nb, 256, 0, stream>>>(offsets, blockSums, cursor, NA);

  reorder_kernel<<<(num_edges + 255) / 256, 256, 0, stream>>>(
      author_ids, paper_ids, cursor, csr, num_edges);

  accumulate_kernel<<<(NA + 3) / 4, 256, 0, stream>>>(
      paper_hb, csr, offsets, counts_int, author_in);

  gemm_mfma<true><<<(NA + 63) / 64, 256, 0, stream>>>(
      author_in, WtA, b_author, counts_int, author_hb, NA);

  dot_kernel<<<(num_label + 3) / 4, 256, 0, stream>>>(
      author_hb, paper_hb, label_author_ids, label_paper_ids, out, num_label);
}

// Round 3
// 885.405 us; speedup vs baseline: 2.6701x; 1.1764x over previous
//
#include <hip/hip_runtime.h>

typedef __attribute__((ext_vector_type(8))) short short8;
typedef __attribute__((ext_vector_type(8))) unsigned short ushort8;
typedef __attribute__((ext_vector_type(4))) float floatx4;

#define NUM_AUTHORS 200000
#define HID 128
#define LDK 136  // LDS row stride in bf16 elems (128 + 8 pad, 16B-aligned)

__device__ __forceinline__ unsigned short f32_to_bf16(float f) {
  union { float f; unsigned int u; } v; v.f = f;
  unsigned int u = v.u;
  u += 0x7FFF + ((u >> 16) & 1);   // round-to-nearest-even
  return (unsigned short)(u >> 16);
}
__device__ __forceinline__ float bf16_to_f32(unsigned short h) {
  union { unsigned int u; float f; } v; v.u = ((unsigned int)h) << 16; return v.f;
}

// Transpose + convert W[128][128] fp32 -> Wt[n][k] bf16. blockIdx.x selects matrix.
__global__ __launch_bounds__(256) void prep_w(
    const float* __restrict__ Wp, const float* __restrict__ Wa,
    unsigned short* __restrict__ WtP, unsigned short* __restrict__ WtA)
{
  const float* W = blockIdx.x ? Wa : Wp;
  unsigned short* Wt = blockIdx.x ? WtA : WtP;
  int t = threadIdx.x;
#pragma unroll
  for (int i = 0; i < 64; ++i) {
    int g = i * 256 + t;
    int k = g >> 7, n = g & 127;
    Wt[n * HID + k] = f32_to_bf16(W[k * HID + n]);
  }
}

// Y[M,128](bf16) = rowscale(X[M,128]) @ W[128,128] + bias
// rowscale = 1/max(counts[row],1) if counts != nullptr
template<bool X_IS_BF16>
__global__ __launch_bounds__(256) void gemm_mfma(
    const void* __restrict__ Xv, const unsigned short* __restrict__ Wt,
    const float* __restrict__ bias, const int* __restrict__ counts,
    unsigned short* __restrict__ Y, int M)
{
  __shared__ unsigned short As[64 * LDK];    // X tile, bf16 [row][k]
  __shared__ unsigned short Bs[128 * LDK];   // Wt,     bf16 [col][k]
  const int t = threadIdx.x;
  const int row0 = blockIdx.x * 64;

  // stage Wt -> Bs (16B chunks)
#pragma unroll
  for (int i = 0; i < 8; ++i) {
    int g = i * 256 + t;           // 2048 groups of 8 elems
    int n = g >> 4;
    int k8 = (g & 15) * 8;
    *(ushort8*)&Bs[n * LDK + k8] = *(const ushort8*)&Wt[n * HID + k8];
  }
  // stage X -> As
#pragma unroll
  for (int i = 0; i < 4; ++i) {
    int g = i * 256 + t;           // 1024 groups of 8 elems
    int r = g >> 4;
    int k8 = (g & 15) * 8;
    int row = row0 + r;
    ushort8 h;
    if (X_IS_BF16) {
      const unsigned short* X = (const unsigned short*)Xv;
      if (row < M) h = *(const ushort8*)(X + (size_t)row * HID + k8);
      else { ushort8 z = (ushort8)0; h = z; }
    } else {
      const float* X = (const float*)Xv;
      float xv[8];
      if (row < M) {
        const float4* src = (const float4*)(X + (size_t)row * HID + k8);
        float4 x0 = src[0], x1 = src[1];
        xv[0]=x0.x; xv[1]=x0.y; xv[2]=x0.z; xv[3]=x0.w;
        xv[4]=x1.x; xv[5]=x1.y; xv[6]=x1.z; xv[7]=x1.w;
      } else {
#pragma unroll
        for (int j = 0; j < 8; ++j) xv[j] = 0.f;
      }
#pragma unroll
      for (int j = 0; j < 8; ++j) h[j] = f32_to_bf16(xv[j]);
    }
    *(ushort8*)&As[r * LDK + k8] = h;
  }
  __syncthreads();

  const int w = t >> 6;        // wave id: rows w*16..w*16+15
  const int lane = t & 63;
  const int m = lane & 15;     // A row / B col / D col
  const int q = lane >> 4;     // quad

  floatx4 acc[8];
#pragma unroll
  for (int c = 0; c < 8; ++c) acc[c] = (floatx4)(0.f);

#pragma unroll
  for (int ks = 0; ks < 4; ++ks) {
    const int koff = ks * 32 + q * 8;
    short8 a = *(const short8*)&As[(w * 16 + m) * LDK + koff];
#pragma unroll
    for (int c = 0; c < 8; ++c) {
      short8 b = *(const short8*)&Bs[(c * 16 + m) * LDK + koff];
      acc[c] = __builtin_amdgcn_mfma_f32_16x16x32_bf16(a, b, acc[c], 0, 0, 0);
    }
  }

  // epilogue: D lane(m,q) reg j -> row q*4+j, col m (within tiles)
  const int rbase = row0 + w * 16 + q * 4;
  float inv[4];
#pragma unroll
  for (int j = 0; j < 4; ++j) {
    if (counts) {
      int row = rbase + j;
      float c = (row < M) ? (float)counts[row] : 1.0f;
      inv[j] = 1.0f / fmaxf(c, 1.0f);
    } else {
      inv[j] = 1.0f;
    }
  }
#pragma unroll
  for (int c = 0; c < 8; ++c) {
    const int col = c * 16 + m;
    const float bv = bias[col];
#pragma unroll
    for (int j = 0; j < 4; ++j) {
      int row = rbase + j;
      if (row < M) Y[(size_t)row * HID + col] = f32_to_bf16(acc[c][j] * inv[j] + bv);
    }
  }
}

// ---- CSR build ----
__global__ __launch_bounds__(256) void hist_kernel(
    const int* __restrict__ aid, int* __restrict__ cnt, int n)
{
  int i = blockIdx.x * 256 + threadIdx.x;
  if (i < n) atomicAdd(&cnt[aid[i]], 1);
}

__global__ __launch_bounds__(256) void scan1(
    const int* __restrict__ cnt, int* __restrict__ offsets,
    int* __restrict__ blockSums, int n)
{
  __shared__ int s[256];
  int t = threadIdx.x;
  int i = blockIdx.x * 256 + t;
  int v = (i < n) ? cnt[i] : 0;
  s[t] = v; __syncthreads();
#pragma unroll
  for (int off = 1; off < 256; off <<= 1) {
    int tv = 0;
    if (t >= off) tv = s[t - off];
    __syncthreads();
    if (t >= off) s[t] += tv;
    __syncthreads();
  }
  if (i < n) offsets[i] = s[t] - v;       // exclusive within block
  if (t == 255) blockSums[blockIdx.x] = s[255];
}

__global__ __launch_bounds__(1024) void scan2(int* __restrict__ blockSums, int nb)
{
  __shared__ int s[1024];
  int t = threadIdx.x;
  int v = (t < nb) ? blockSums[t] : 0;
  s[t] = v; __syncthreads();
#pragma unroll
  for (int off = 1; off < 1024; off <<= 1) {
    int tv = 0;
    if (t >= off) tv = s[t - off];
    __syncthreads();
    if (t >= off) s[t] += tv;
    __syncthreads();
  }
  if (t < nb) blockSums[t] = s[t] - v;    // exclusive
}

__global__ __launch_bounds__(256) void scan3(
    int* __restrict__ offsets, const int* __restrict__ blockSums,
    int* __restrict__ cursor, int n)
{
  int i = blockIdx.x * 256 + threadIdx.x;
  if (i < n) {
    int o = offsets[i] + blockSums[blockIdx.x];
    offsets[i] = o;
    cursor[i]  = o;
  }
}

__global__ __launch_bounds__(256) void reorder_kernel(
    const int* __restrict__ aid, const int* __restrict__ pid,
    int* __restrict__ cursor, int* __restrict__ csr, int n)
{
  int e = blockIdx.x * 256 + threadIdx.x;
  if (e < n) {
    int a = aid[e];
    int pos = atomicAdd(&cursor[a], 1);
    csr[pos] = pid[e];
  }
}

// One wave per author; 4x16-lane groups each gather one 256B row per iter
// via dwordx4 (16B/lane). Cross-group reduce at the end.
__global__ __launch_bounds__(256) void accumulate_kernel(
    const unsigned short* __restrict__ paper_hb, const int* __restrict__ csr,
    const int* __restrict__ offsets, const int* __restrict__ cnt,
    unsigned short* __restrict__ author_in)
{
  int a = blockIdx.x * 4 + (threadIdx.x >> 6);
  if (a >= NUM_AUTHORS) return;
  int lane = threadIdx.x & 63;
  int sub = lane >> 4;      // row-group 0..3
  int c16 = lane & 15;      // column sixteenth: cols c16*8 .. +7
  int start = offsets[a];
  int n = cnt[a];
  float acc[8];
#pragma unroll
  for (int j = 0; j < 8; ++j) acc[j] = 0.f;
  for (int i = 0; i < n; i += 4) {
    int idx = i + sub;
    if (idx < n) {
      int p = csr[start + idx];
      ushort8 h = *(const ushort8*)(paper_hb + (size_t)p * HID + c16 * 8);
#pragma unroll
      for (int j = 0; j < 8; ++j) acc[j] += bf16_to_f32(h[j]);
    }
  }
#pragma unroll
  for (int j = 0; j < 8; ++j) {
    acc[j] += __shfl_xor(acc[j], 16, 64);
    acc[j] += __shfl_xor(acc[j], 32, 64);
  }
  if (sub == 0) {
    ushort8 o;
#pragma unroll
    for (int j = 0; j < 8; ++j) o[j] = f32_to_bf16(acc[j]);
    *(ushort8*)(author_in + (size_t)a * HID + c16 * 8) = o;
  }
}

// One edge per 16-lane group (4 edges/wave, 16 edges/block); 16B loads/lane.
__global__ __launch_bounds__(256) void dot_kernel(
    const unsigned short* __restrict__ author_hb, const unsigned short* __restrict__ paper_hb,
    const int* __restrict__ la, const int* __restrict__ lp,
    float* __restrict__ out, int n)
{
  int e = blockIdx.x * 16 + (threadIdx.x >> 4);
  if (e >= n) return;
  int c16 = threadIdx.x & 15;
  int a = la[e], p = lp[e];
  ushort8 ah = *(const ushort8*)(author_hb + (size_t)a * HID + c16 * 8);
  ushort8 ph = *(const ushort8*)(paper_hb + (size_t)p * HID + c16 * 8);
  float s = 0.f;
#pragma unroll
  for (int j = 0; j < 8; ++j) s += bf16_to_f32(ah[j]) * bf16_to_f32(ph[j]);
  s += __shfl_xor(s, 1, 64);
  s += __shfl_xor(s, 2, 64);
  s += __shfl_xor(s, 4, 64);
  s += __shfl_xor(s, 8, 64);
  if (c16 == 0) out[e] = s;
}

extern "C" void kernel_launch(void* const* d_in, const int* in_sizes, int n_in,
                              void* d_out, int out_size, void* d_ws, size_t ws_size,
                              hipStream_t stream)
{
  const float* paper_x          = (const float*)d_in[0];
  const int*   author_ids       = (const int*)d_in[1];
  const int*   paper_ids        = (const int*)d_in[2];
  const int*   label_author_ids = (const int*)d_in[3];
  const int*   label_paper_ids  = (const int*)d_in[4];
  const float* W_paper          = (const float*)d_in[5];
  const float* b_paper          = (const float*)d_in[6];
  const float* W_author         = (const float*)d_in[7];
  const float* b_author         = (const float*)d_in[8];
  float* out = (float*)d_out;

  const int num_papers = in_sizes[0] / HID;
  const int num_edges  = in_sizes[1];
  const int num_label  = in_sizes[3];
  const int NA = NUM_AUTHORS;

  char* ws = (char*)d_ws;
  size_t off = 0;
  auto alloc = [&](size_t bytes) { void* p = ws + off; off = (off + bytes + 255) & ~(size_t)255; return p; };
  unsigned short* paper_hb  = (unsigned short*)alloc((size_t)num_papers * HID * 2);
  unsigned short* author_in = (unsigned short*)alloc((size_t)NA * HID * 2);
  unsigned short* author_hb = (unsigned short*)alloc((size_t)NA * HID * 2);
  int* counts_int = (int*)alloc((size_t)NA * 4);
  int* offsets    = (int*)alloc((size_t)NA * 4);
  int* cursor     = (int*)alloc((size_t)NA * 4);
  int* blockSums  = (int*)alloc(1024 * 4);
  int* csr        = (int*)alloc((size_t)num_edges * 4);
  unsigned short* WtP = (unsigned short*)alloc(HID * HID * 2);
  unsigned short* WtA = (unsigned short*)alloc(HID * HID * 2);

  hipMemsetAsync(counts_int, 0, (size_t)NA * 4, stream);

  prep_w<<<2, 256, 0, stream>>>(W_paper, W_author, WtP, WtA);

  gemm_mfma<false><<<(num_papers + 63) / 64, 256, 0, stream>>>(
      paper_x, WtP, b_paper, nullptr, paper_hb, num_papers);

  hist_kernel<<<(num_edges + 255) / 256, 256, 0, stream>>>(author_ids, counts_int, num_edges);

  const int nb = (NA + 255) / 256;   // 782 <= 1024
  scan1<<<nb, 256, 0, stream>>>(counts_int, offsets, blockSums, NA);
  scan2<<<1, 1024, 0, stream>>>(blockSums, nb);
  scan3<<<nb, 256, 0, stream>>>(offsets, blockSums, cursor, NA);

  reorder_kernel<<<(num_edges + 255) / 256, 256, 0, stream>>>(
      author_ids, paper_ids, cursor, csr, num_edges);

  accumulate_kernel<<<(NA + 3) / 4, 256, 0, stream>>>(
      paper_hb, csr, offsets, counts_int, author_in);

  gemm_mfma<true><<<(NA + 63) / 64, 256, 0, stream>>>(
      author_in, WtA, b_author, counts_int, author_hb, NA);

  dot_kernel<<<(num_label + 15) / 16, 256, 0, stream>>>(
      author_hb, paper_hb, label_author_ids, label_paper_ids, out, num_label);
}

// Round 4
// 809.428 us; speedup vs baseline: 2.9207x; 1.0939x over previous
//
#include <hip/hip_runtime.h>

typedef __attribute__((ext_vector_type(8))) short short8;
typedef __attribute__((ext_vector_type(8))) unsigned short ushort8;
typedef __attribute__((ext_vector_type(4))) float floatx4;

#define NUM_AUTHORS 200000
#define HID 128
#define LDK 136   // LDS row stride in bf16 elems (128 + 8 pad, 16B-aligned)
#define ABITS 9   // 512 authors per bucket
#define NB 391    // ceil(200000 / 512)
#define CHUNK 8192

__device__ __forceinline__ unsigned short f32_to_bf16(float f) {
  union { float f; unsigned int u; } v; v.f = f;
  unsigned int u = v.u;
  u += 0x7FFF + ((u >> 16) & 1);   // round-to-nearest-even
  return (unsigned short)(u >> 16);
}
__device__ __forceinline__ float bf16_to_f32(unsigned short h) {
  union { unsigned int u; float f; } v; v.u = ((unsigned int)h) << 16; return v.f;
}

// Transpose + convert W[128][128] fp32 -> Wt[n][k] bf16. blockIdx.x selects matrix.
__global__ __launch_bounds__(256) void prep_w(
    const float* __restrict__ Wp, const float* __restrict__ Wa,
    unsigned short* __restrict__ WtP, unsigned short* __restrict__ WtA)
{
  const float* W = blockIdx.x ? Wa : Wp;
  unsigned short* Wt = blockIdx.x ? WtA : WtP;
  int t = threadIdx.x;
#pragma unroll
  for (int i = 0; i < 64; ++i) {
    int g = i * 256 + t;
    int k = g >> 7, n = g & 127;
    Wt[n * HID + k] = f32_to_bf16(W[k * HID + n]);
  }
}

// Y[M,128](bf16) = rowscale(X[M,128]) @ W[128,128] + bias
template<bool X_IS_BF16>
__global__ __launch_bounds__(256) void gemm_mfma(
    const void* __restrict__ Xv, const unsigned short* __restrict__ Wt,
    const float* __restrict__ bias, const int* __restrict__ counts,
    unsigned short* __restrict__ Y, int M)
{
  __shared__ unsigned short As[64 * LDK];
  __shared__ unsigned short Bs[128 * LDK];
  const int t = threadIdx.x;
  const int row0 = blockIdx.x * 64;

#pragma unroll
  for (int i = 0; i < 8; ++i) {
    int g = i * 256 + t;
    int n = g >> 4;
    int k8 = (g & 15) * 8;
    *(ushort8*)&Bs[n * LDK + k8] = *(const ushort8*)&Wt[n * HID + k8];
  }
#pragma unroll
  for (int i = 0; i < 4; ++i) {
    int g = i * 256 + t;
    int r = g >> 4;
    int k8 = (g & 15) * 8;
    int row = row0 + r;
    ushort8 h;
    if (X_IS_BF16) {
      const unsigned short* X = (const unsigned short*)Xv;
      if (row < M) h = *(const ushort8*)(X + (size_t)row * HID + k8);
      else { ushort8 z = (ushort8)0; h = z; }
    } else {
      const float* X = (const float*)Xv;
      float xv[8];
      if (row < M) {
        const float4* src = (const float4*)(X + (size_t)row * HID + k8);
        float4 x0 = src[0], x1 = src[1];
        xv[0]=x0.x; xv[1]=x0.y; xv[2]=x0.z; xv[3]=x0.w;
        xv[4]=x1.x; xv[5]=x1.y; xv[6]=x1.z; xv[7]=x1.w;
      } else {
#pragma unroll
        for (int j = 0; j < 8; ++j) xv[j] = 0.f;
      }
#pragma unroll
      for (int j = 0; j < 8; ++j) h[j] = f32_to_bf16(xv[j]);
    }
    *(ushort8*)&As[r * LDK + k8] = h;
  }
  __syncthreads();

  const int w = t >> 6;
  const int lane = t & 63;
  const int m = lane & 15;
  const int q = lane >> 4;

  floatx4 acc[8];
#pragma unroll
  for (int c = 0; c < 8; ++c) acc[c] = (floatx4)(0.f);

#pragma unroll
  for (int ks = 0; ks < 4; ++ks) {
    const int koff = ks * 32 + q * 8;
    short8 a = *(const short8*)&As[(w * 16 + m) * LDK + koff];
#pragma unroll
    for (int c = 0; c < 8; ++c) {
      short8 b = *(const short8*)&Bs[(c * 16 + m) * LDK + koff];
      acc[c] = __builtin_amdgcn_mfma_f32_16x16x32_bf16(a, b, acc[c], 0, 0, 0);
    }
  }

  const int rbase = row0 + w * 16 + q * 4;
  float inv[4];
#pragma unroll
  for (int j = 0; j < 4; ++j) {
    if (counts) {
      int row = rbase + j;
      float c = (row < M) ? (float)counts[row] : 1.0f;
      inv[j] = 1.0f / fmaxf(c, 1.0f);
    } else {
      inv[j] = 1.0f;
    }
  }
#pragma unroll
  for (int c = 0; c < 8; ++c) {
    const int col = c * 16 + m;
    const float bv = bias[col];
#pragma unroll
    for (int j = 0; j < 4; ++j) {
      int row = rbase + j;
      if (row < M) Y[(size_t)row * HID + col] = f32_to_bf16(acc[c][j] * inv[j] + bv);
    }
  }
}

// ---- author-count histogram + scan (for offsets/cnt) ----
__global__ __launch_bounds__(256) void hist_kernel(
    const int* __restrict__ aid, int* __restrict__ cnt, int n)
{
  int i = blockIdx.x * 256 + threadIdx.x;
  if (i < n) atomicAdd(&cnt[aid[i]], 1);
}

__global__ __launch_bounds__(256) void scan1(
    const int* __restrict__ cnt, int* __restrict__ offsets,
    int* __restrict__ blockSums, int n)
{
  __shared__ int s[256];
  int t = threadIdx.x;
  int i = blockIdx.x * 256 + t;
  int v = (i < n) ? cnt[i] : 0;
  s[t] = v; __syncthreads();
#pragma unroll
  for (int off = 1; off < 256; off <<= 1) {
    int tv = 0;
    if (t >= off) tv = s[t - off];
    __syncthreads();
    if (t >= off) s[t] += tv;
    __syncthreads();
  }
  if (i < n) offsets[i] = s[t] - v;
  if (t == 255) blockSums[blockIdx.x] = s[255];
}

__global__ __launch_bounds__(1024) void scan2(int* __restrict__ blockSums, int nb)
{
  __shared__ int s[1024];
  int t = threadIdx.x;
  int v = (t < nb) ? blockSums[t] : 0;
  s[t] = v; __syncthreads();
#pragma unroll
  for (int off = 1; off < 1024; off <<= 1) {
    int tv = 0;
    if (t >= off) tv = s[t - off];
    __syncthreads();
    if (t >= off) s[t] += tv;
    __syncthreads();
  }
  if (t < nb) blockSums[t] = s[t] - v;
}

__global__ __launch_bounds__(256) void scan3(
    int* __restrict__ offsets, const int* __restrict__ blockSums, int n)
{
  int i = blockIdx.x * 256 + threadIdx.x;
  if (i < n) offsets[i] += blockSums[blockIdx.x];
}

// ---- two-level radix partition ----
// edges-per-bucket histogram, block-aggregated
__global__ __launch_bounds__(256) void bucket_hist(
    const int* __restrict__ aid, int* __restrict__ bcnt, int n)
{
  __shared__ int hist[NB];
  int t = threadIdx.x;
  for (int i = t; i < NB; i += 256) hist[i] = 0;
  __syncthreads();
  int e0 = blockIdx.x * CHUNK;
  int e1 = min(e0 + CHUNK, n);
  for (int e = e0 + t; e < e1; e += 256) atomicAdd(&hist[aid[e] >> ABITS], 1);
  __syncthreads();
  for (int i = t; i < NB; i += 256) {
    int h = hist[i];
    if (h) atomicAdd(&bcnt[i], h);
  }
}

// single-block exclusive scan of bucket counts -> boff and bcur
__global__ __launch_bounds__(512) void bucket_scan(
    const int* __restrict__ bcnt, int* __restrict__ boff, int* __restrict__ bcur, int n)
{
  __shared__ int s[512];
  int t = threadIdx.x;
  int v = (t < NB) ? bcnt[t] : 0;
  s[t] = v; __syncthreads();
#pragma unroll
  for (int off = 1; off < 512; off <<= 1) {
    int tv = 0;
    if (t >= off) tv = s[t - off];
    __syncthreads();
    if (t >= off) s[t] += tv;
    __syncthreads();
  }
  if (t < NB) { int e = s[t] - v; boff[t] = e; bcur[t] = e; }
  if (t == 0) boff[NB] = n;
}

// partition (aid,pid) pairs bucket-major; LDS-binned so same-bucket pairs
// from one block land contiguously (no 64B-line write amplification)
__global__ __launch_bounds__(256) void partA(
    const int* __restrict__ aid, const int* __restrict__ pid,
    int* __restrict__ bcur, uint2* __restrict__ pairs, int n)
{
  __shared__ int hist[NB];
  __shared__ int cur[NB];
  int t = threadIdx.x;
  for (int i = t; i < NB; i += 256) hist[i] = 0;
  __syncthreads();
  int e0 = blockIdx.x * CHUNK;
  int e1 = min(e0 + CHUNK, n);
  for (int e = e0 + t; e < e1; e += 256) atomicAdd(&hist[aid[e] >> ABITS], 1);
  __syncthreads();
  for (int i = t; i < NB; i += 256) {
    int h = hist[i];
    cur[i] = h ? atomicAdd(&bcur[i], h) : 0;
  }
  __syncthreads();
  for (int e = e0 + t; e < e1; e += 256) {
    int a = aid[e];
    int pos = atomicAdd(&cur[a >> ABITS], 1);
    pairs[pos] = make_uint2((unsigned)a, (unsigned)pid[e]);
  }
}

// one block per bucket: scatter pids into this bucket's csr window (~20 KB,
// single-XCD L2-resident) using per-author LDS cursors
__global__ __launch_bounds__(256) void partB(
    const uint2* __restrict__ pairs, const int* __restrict__ boff,
    const int* __restrict__ offsets, int* __restrict__ csr)
{
  __shared__ int lcur[1 << ABITS];
  int b = blockIdx.x;
  int t = threadIdx.x;
  int a0 = b << ABITS;
  for (int i = t; i < (1 << ABITS); i += 256) {
    int g = a0 + i;
    lcur[i] = (g < NUM_AUTHORS) ? offsets[g] : 0;
  }
  __syncthreads();
  int s = boff[b], e = boff[b + 1];
  for (int i = s + t; i < e; i += 256) {
    uint2 pr = pairs[i];
    int pos = atomicAdd(&lcur[pr.x - a0], 1);
    csr[pos] = (int)pr.y;
  }
}

// One wave per author; 4x16-lane groups each gather one 256B row per iter.
__global__ __launch_bounds__(256) void accumulate_kernel(
    const unsigned short* __restrict__ paper_hb, const int* __restrict__ csr,
    const int* __restrict__ offsets, const int* __restrict__ cnt,
    unsigned short* __restrict__ author_in)
{
  int a = blockIdx.x * 4 + (threadIdx.x >> 6);
  if (a >= NUM_AUTHORS) return;
  int lane = threadIdx.x & 63;
  int sub = lane >> 4;
  int c16 = lane & 15;
  int start = offsets[a];
  int n = cnt[a];
  float acc[8];
#pragma unroll
  for (int j = 0; j < 8; ++j) acc[j] = 0.f;
  for (int i = 0; i < n; i += 4) {
    int idx = i + sub;
    if (idx < n) {
      int p = csr[start + idx];
      ushort8 h = *(const ushort8*)(paper_hb + (size_t)p * HID + c16 * 8);
#pragma unroll
      for (int j = 0; j < 8; ++j) acc[j] += bf16_to_f32(h[j]);
    }
  }
#pragma unroll
  for (int j = 0; j < 8; ++j) {
    acc[j] += __shfl_xor(acc[j], 16, 64);
    acc[j] += __shfl_xor(acc[j], 32, 64);
  }
  if (sub == 0) {
    ushort8 o;
#pragma unroll
    for (int j = 0; j < 8; ++j) o[j] = f32_to_bf16(acc[j]);
    *(ushort8*)(author_in + (size_t)a * HID + c16 * 8) = o;
  }
}

// One edge per 16-lane group; 16B loads/lane.
__global__ __launch_bounds__(256) void dot_kernel(
    const unsigned short* __restrict__ author_hb, const unsigned short* __restrict__ paper_hb,
    const int* __restrict__ la, const int* __restrict__ lp,
    float* __restrict__ out, int n)
{
  int e = blockIdx.x * 16 + (threadIdx.x >> 4);
  if (e >= n) return;
  int c16 = threadIdx.x & 15;
  int a = la[e], p = lp[e];
  ushort8 ah = *(const ushort8*)(author_hb + (size_t)a * HID + c16 * 8);
  ushort8 ph = *(const ushort8*)(paper_hb + (size_t)p * HID + c16 * 8);
  float s = 0.f;
#pragma unroll
  for (int j = 0; j < 8; ++j) s += bf16_to_f32(ah[j]) * bf16_to_f32(ph[j]);
  s += __shfl_xor(s, 1, 64);
  s += __shfl_xor(s, 2, 64);
  s += __shfl_xor(s, 4, 64);
  s += __shfl_xor(s, 8, 64);
  if (c16 == 0) out[e] = s;
}

extern "C" void kernel_launch(void* const* d_in, const int* in_sizes, int n_in,
                              void* d_out, int out_size, void* d_ws, size_t ws_size,
                              hipStream_t stream)
{
  const float* paper_x          = (const float*)d_in[0];
  const int*   author_ids       = (const int*)d_in[1];
  const int*   paper_ids        = (const int*)d_in[2];
  const int*   label_author_ids = (const int*)d_in[3];
  const int*   label_paper_ids  = (const int*)d_in[4];
  const float* W_paper          = (const float*)d_in[5];
  const float* b_paper          = (const float*)d_in[6];
  const float* W_author         = (const float*)d_in[7];
  const float* b_author         = (const float*)d_in[8];
  float* out = (float*)d_out;

  const int num_papers = in_sizes[0] / HID;
  const int num_edges  = in_sizes[1];
  const int num_label  = in_sizes[3];
  const int NA = NUM_AUTHORS;

  char* ws = (char*)d_ws;
  size_t off = 0;
  auto alloc = [&](size_t bytes) { void* p = ws + off; off = (off + bytes + 255) & ~(size_t)255; return p; };
  unsigned short* paper_hb  = (unsigned short*)alloc((size_t)num_papers * HID * 2);
  unsigned short* author_in = (unsigned short*)alloc((size_t)NA * HID * 2);
  unsigned short* author_hb = (unsigned short*)alloc((size_t)NA * HID * 2);
  int* counts_int = (int*)alloc((size_t)NA * 4);
  int* bcnt       = (int*)alloc((size_t)(NB + 1) * 4);     // contiguous after counts_int? (alloc aligns; memset separately)
  int* boff       = (int*)alloc((size_t)(NB + 1) * 4);
  int* bcur       = (int*)alloc((size_t)NB * 4);
  int* offsets    = (int*)alloc((size_t)NA * 4);
  int* blockSums  = (int*)alloc(1024 * 4);
  int* csr        = (int*)alloc((size_t)num_edges * 4);
  uint2* pairs    = (uint2*)alloc((size_t)num_edges * 8);
  unsigned short* WtP = (unsigned short*)alloc(HID * HID * 2);
  unsigned short* WtA = (unsigned short*)alloc(HID * HID * 2);

  hipMemsetAsync(counts_int, 0, (size_t)NA * 4, stream);
  hipMemsetAsync(bcnt, 0, (size_t)(NB + 1) * 4, stream);

  prep_w<<<2, 256, 0, stream>>>(W_paper, W_author, WtP, WtA);

  gemm_mfma<false><<<(num_papers + 63) / 64, 256, 0, stream>>>(
      paper_x, WtP, b_paper, nullptr, paper_hb, num_papers);

  hist_kernel<<<(num_edges + 255) / 256, 256, 0, stream>>>(author_ids, counts_int, num_edges);

  const int nb = (NA + 255) / 256;   // 782 <= 1024
  scan1<<<nb, 256, 0, stream>>>(counts_int, offsets, blockSums, NA);
  scan2<<<1, 1024, 0, stream>>>(blockSums, nb);
  scan3<<<nb, 256, 0, stream>>>(offsets, blockSums, NA);

  const int nchunks = (num_edges + CHUNK - 1) / CHUNK;
  bucket_hist<<<nchunks, 256, 0, stream>>>(author_ids, bcnt, num_edges);
  bucket_scan<<<1, 512, 0, stream>>>(bcnt, boff, bcur, num_edges);
  partA<<<nchunks, 256, 0, stream>>>(author_ids, paper_ids, bcur, pairs, num_edges);
  partB<<<NB, 256, 0, stream>>>(pairs, boff, offsets, csr);

  accumulate_kernel<<<(NA + 3) / 4, 256, 0, stream>>>(
      paper_hb, csr, offsets, counts_int, author_in);

  gemm_mfma<true><<<(NA + 63) / 64, 256, 0, stream>>>(
      author_in, WtA, b_author, counts_int, author_hb, NA);

  dot_kernel<<<(num_label + 15) / 16, 256, 0, stream>>>(
      author_hb, paper_hb, label_author_ids, label_paper_ids, out, num_label);
}